// Round 2
// baseline (1624.487 us; speedup 1.0000x reference)
//
#include <hip/hip_runtime.h>

typedef unsigned short u16;
typedef __attribute__((ext_vector_type(8))) short bf16x8;
typedef __attribute__((ext_vector_type(4))) float f32x4;

__device__ __forceinline__ float bf2f(u16 u){
  union { unsigned int i; float f; } x; x.i = ((unsigned int)u) << 16; return x.f;
}
__device__ __forceinline__ u16 f2bf(float f){
  union { float f; unsigned int i; } x; x.f = f;
  unsigned int r = x.i + 0x7fffu + ((x.i >> 16) & 1u);
  return (u16)(r >> 16);
}

// ---------------- f32 -> bf16 convert (vectorized) ----------------
__global__ __launch_bounds__(256) void cvt_f32_bf16(const float* __restrict__ in,
                                                    u16* __restrict__ out, int n4){
  int i = blockIdx.x*256 + threadIdx.x;
  if (i < n4){
    float4 v = reinterpret_cast<const float4*>(in)[i];
    ushort4 o = make_ushort4(f2bf(v.x), f2bf(v.y), f2bf(v.z), f2bf(v.w));
    reinterpret_cast<ushort4*>(out)[i] = o;
  }
}

// ---------------- bf16 MFMA GEMM: C[M][N] = A[M][K] * Bt[N][K]^T ----
// m97 structure: 128x128 tile, BK=64, global_load_lds width 16.
// OBF=1 -> bf16 output, OBF=0 -> f32 output.
template<int GUARD, int OBF>
__global__ __launch_bounds__(256) void gemm_bt(
    const u16* __restrict__ A, int lda,
    const u16* __restrict__ Bt, int ldb,
    void* __restrict__ Cp, int ldc,
    int M, int N, int K)
{
  __shared__ __align__(16) u16 As[128*64];
  __shared__ __align__(16) u16 Bs[128*64];
  const int tid  = threadIdx.x;
  const int wid  = tid >> 6;
  const int lane = tid & 63;
  const int m0 = blockIdx.y * 128;
  const int n0 = blockIdx.x * 128;
  const int wr = wid >> 1, wc = wid & 1;
  const int lq = lane >> 4, lr = lane & 15;

  f32x4 acc[4][4];
  #pragma unroll
  for (int m=0;m<4;m++)
    #pragma unroll
    for (int n=0;n<4;n++) acc[m][n] = (f32x4){0.f,0.f,0.f,0.f};

  const int srow = wid*32 + (lane>>3);   // row this lane stages (per 8-row issue)
  const int scol = (lane&7)*8;           // k-offset this lane stages

  for (int k0=0; k0<K; k0+=64){
    #pragma unroll
    for (int i=0;i<4;i++){
      const u16* ga = A + (size_t)(m0 + srow + i*8)*lda + k0 + scol;
      __builtin_amdgcn_global_load_lds(
        (const __attribute__((address_space(1))) void*)ga,
        (__attribute__((address_space(3))) void*)&As[(wid*32+i*8)*64], 16, 0, 0);
    }
    #pragma unroll
    for (int i=0;i<4;i++){
      int gn = n0 + srow + i*8;
      if (GUARD) gn = (gn < N) ? gn : (N-1);
      const u16* gb = Bt + (size_t)gn*ldb + k0 + scol;
      __builtin_amdgcn_global_load_lds(
        (const __attribute__((address_space(1))) void*)gb,
        (__attribute__((address_space(3))) void*)&Bs[(wid*32+i*8)*64], 16, 0, 0);
    }
    __syncthreads();
    #pragma unroll
    for (int kk=0;kk<2;kk++){
      bf16x8 af[4], bfr[4];
      #pragma unroll
      for (int m=0;m<4;m++)
        af[m] = *reinterpret_cast<const bf16x8*>(&As[(wr*64 + m*16 + lr)*64 + kk*32 + lq*8]);
      #pragma unroll
      for (int n=0;n<4;n++)
        bfr[n] = *reinterpret_cast<const bf16x8*>(&Bs[(wc*64 + n*16 + lr)*64 + kk*32 + lq*8]);
      #pragma unroll
      for (int m=0;m<4;m++)
        #pragma unroll
        for (int n=0;n<4;n++)
          acc[m][n] = __builtin_amdgcn_mfma_f32_16x16x32_bf16(af[m], bfr[n], acc[m][n], 0,0,0);
    }
    __syncthreads();
  }

  #pragma unroll
  for (int m=0;m<4;m++){
    int row = m0 + wr*64 + m*16 + lq*4;
    #pragma unroll
    for (int n=0;n<4;n++){
      int col = n0 + wc*64 + n*16 + lr;
      if (!GUARD || col < N){
        #pragma unroll
        for (int j=0;j<4;j++){
          if (OBF) ((u16*)Cp)[(size_t)(row+j)*ldc + col] = f2bf(acc[m][n][j]);
          else     ((float*)Cp)[(size_t)(row+j)*ldc + col] = acc[m][n][j];
        }
      }
    }
  }
}

// ---------------- depthwise conv7 (SAME) + bias + SiLU -> bf16 ----------------
// input: zxb[8192][4416] bf16, channels [2048,4352) ; output xc[8192][2304] bf16
__global__ __launch_bounds__(256) void conv_silu(
    const u16* __restrict__ zxb, const float* __restrict__ w,
    const float* __restrict__ bias, u16* __restrict__ xc)
{
  int idx = blockIdx.x*256 + threadIdx.x;   // 8192*288 units of 8 channels
  if (idx >= 8192*288) return;
  int g   = idx % 288;
  int row = idx / 288;
  int l = row & 4095;
  int c = g*8;
  float a[8];
  #pragma unroll
  for (int j=0;j<8;j++) a[j] = bias[c+j];
  #pragma unroll
  for (int t=0;t<7;t++){
    int ls = l + t - 3;
    if (ls >= 0 && ls < 4096){
      bf16x8 v = *reinterpret_cast<const bf16x8*>(&zxb[(size_t)(row + (ls - l))*4416 + 2048 + c]);
      #pragma unroll
      for (int j=0;j<8;j++) a[j] += bf2f((u16)v[j]) * w[(c+j)*7+t];
    }
  }
  bf16x8 o;
  #pragma unroll
  for (int j=0;j<8;j++){
    float s = a[j]/(1.f+__expf(-a[j]));
    o[j] = (short)f2bf(s);
  }
  *reinterpret_cast<bf16x8*>(&xc[(size_t)row*2304 + c]) = o;
}

// ---------------- bidirectional selective scan (direct, chunk-staged) --------
// block = (dir, b, h); 4 waves = 4 p-groups of 16; lane owns 16 state elems.
// stores UNSHIFTED y_pre (bf16) in scan-time order; shift/flip resolved in fuse.
__global__ __launch_bounds__(256) void scan_kernel(
    const u16* __restrict__ zxb, const u16* __restrict__ xc,
    const float* __restrict__ dt_bias, const float* __restrict__ A_log,
    u16* __restrict__ ypF, u16* __restrict__ ypB)
{
  const int blk = blockIdx.x;          // 128 blocks
  const int h   = blk & 31;
  const int b   = (blk >> 5) & 1;
  const int dir = blk >> 6;            // 0 fwd, 1 bwd
  const int tid  = threadIdx.x;
  const int lane = tid & 63;
  const int wv   = tid >> 6;
  const int p  = wv*16 + (lane & 15);
  const int nq = lane >> 4;
  const int n0 = nq*16;

  const float Ah  = -__expf(A_log[h]);
  const float dtb = dt_bias[h];

  __shared__ float Bl[64][64];
  __shared__ float Cl[64][64];
  __shared__ float Xl[64][64];
  __shared__ float Dc[64];
  __shared__ float Dt[64];

  float st[16];
  #pragma unroll
  for (int j=0;j<16;j++) st[j]=0.f;

  u16* outp = dir ? ypB : ypF;

  for (int c0=0; c0<4096; c0+=64){
    __syncthreads();
    for (int i=tid; i<64*64; i+=256){
      int t = i >> 6, n = i & 63;
      int lsrc = dir ? (4095 - (c0+t)) : (c0+t);
      size_t rb = (size_t)(b*4096 + lsrc)*2304;
      Bl[t][n] = bf2f(xc[rb + 2048 + dir*128 + n]);
      Cl[t][n] = bf2f(xc[rb + 2112 + dir*128 + n]);
      Xl[t][n] = bf2f(xc[rb + (size_t)h*64 + n]);
    }
    if (tid < 64){
      int t = tid;
      int lsrc = dir ? (4095 - (c0+t)) : (c0+t);
      float raw = bf2f(zxb[(size_t)(b*4096+lsrc)*4416 + 4352 + dir*32 + h]) + dtb;
      float dte = (raw > 20.f) ? raw : log1pf(__expf(raw));
      Dt[t] = dte;
      Dc[t] = __expf(Ah*dte);
    }
    __syncthreads();
    for (int t=0;t<64;t++){
      float dec   = Dc[t];
      float coeff = Dt[t] * Xl[t][p];
      float yp = 0.f;
      #pragma unroll
      for (int j=0;j<16;j++){
        st[j] = st[j]*dec + coeff*Bl[t][n0+j];
        yp   += st[j]*Cl[t][n0+j];
      }
      yp += __shfl_xor(yp, 16, 64);
      yp += __shfl_xor(yp, 32, 64);
      if (nq == 0)
        outp[(size_t)(b*4096 + c0 + t)*2048 + h*64 + p] = f2bf(yp);
    }
  }
}

// ---------------- fuse: y-combine(shift/flip) + D*x + RMSNorm + SiLU(z) ------
// writes un (bf16) into zxb columns [2048,4096) (dead xBC region)
__global__ __launch_bounds__(256) void fuse_rms(
    const u16* __restrict__ ypF, const u16* __restrict__ ypB,
    const u16* __restrict__ xc, u16* __restrict__ zxb,
    const float* __restrict__ Dscal, const float* __restrict__ D_b,
    const float* __restrict__ rms_w)
{
  const int row = blockIdx.x;      // b*4096 + l
  const int l = row & 4095;
  const int tid = threadIdx.x;
  const int c = tid*8;             // 8 consecutive channels
  const int hh = tid >> 3;
  float v[8]; float ss = 0.f;
  const bool hasF = (l >= 1);
  const bool hasB = (l <= 4094);
  bf16x8 yf, yb;
  if (hasF) yf = *reinterpret_cast<const bf16x8*>(&ypF[(size_t)(row-1)*2048 + c]);
  if (hasB) yb = *reinterpret_cast<const bf16x8*>(&ypB[(size_t)(row + 4094 - 2*l)*2048 + c]);
  bf16x8 xv = *reinterpret_cast<const bf16x8*>(&xc[(size_t)row*2304 + c]);
  const float dsc = Dscal[(size_t)row*32 + hh] + D_b[hh];
  #pragma unroll
  for (int i=0;i<8;i++){
    float y = hasF ? bf2f((u16)yf[i]) : 0.f;
    if (hasB) y += bf2f((u16)yb[i]);
    y += dsc * bf2f((u16)xv[i]);
    v[i] = y;
    ss += y*y;
  }
  #pragma unroll
  for (int o=1;o<64;o<<=1) ss += __shfl_xor(ss, o, 64);
  __shared__ float sred[4];
  if ((tid & 63) == 0) sred[tid>>6] = ss;
  __syncthreads();
  float rstd = rsqrtf((sred[0]+sred[1]+sred[2]+sred[3]) * (1.f/2048.f) + 1e-5f);
  bf16x8 zv = *reinterpret_cast<const bf16x8*>(&zxb[(size_t)row*4416 + c]);
  bf16x8 o;
  #pragma unroll
  for (int i=0;i<8;i++){
    float z = bf2f((u16)zv[i]);
    float sz = z / (1.f + __expf(-z));
    o[i] = (short)f2bf(v[i]*rstd*rms_w[c+i]*sz);
  }
  *reinterpret_cast<bf16x8*>(&zxb[(size_t)row*4416 + 2048 + c]) = o;
}

extern "C" void kernel_launch(void* const* d_in, const int* in_sizes, int n_in,
                              void* d_out, int out_size, void* d_ws, size_t ws_size,
                              hipStream_t stream)
{
  const float* u       = (const float*)d_in[0];
  const float* w_in    = (const float*)d_in[1];
  const float* conv_w  = (const float*)d_in[2];
  const float* conv_b  = (const float*)d_in[3];
  const float* dt_bias = (const float*)d_in[4];
  const float* A_log   = (const float*)d_in[5];
  const float* D_w     = (const float*)d_in[6];
  const float* D_b     = (const float*)d_in[7];
  const float* rms_w   = (const float*)d_in[8];
  const float* w_out   = (const float*)d_in[9];
  float* out = (float*)d_out;
  (void)in_sizes; (void)n_in; (void)out_size; (void)ws_size;

  char* ws = (char*)d_ws;
  // ---- workspace layout (total ~174 MiB), with aliasing ----
  u16*   zxb = (u16*)(ws);                                   // 8192*4416 bf16 = 72.35 MB
  u16*   xc  = (u16*)(ws + 72351744);                        // 8192*2304 bf16 = 37.75 MB
  char*  regC =       ws + 72351744 + 37748736;              // 33.55 MB shared region
  u16*   ub  = (u16*)(regC);                                 // 8192*1024 bf16 (dead after gemm1)
  u16*   w1b = (u16*)(regC + 16777216);                      // 4416*1024 bf16 (dead after gemm1)
  u16*   ypF = (u16*)(regC);                                 // 8192*2048 bf16 (born at scan)
  u16*   ypB = (u16*)(regC + 33554432);                      // 8192*2048 bf16 = 33.55 MB
  float* Dsc = (float*)(regC + 33554432 + 33554432);         // 8192*32 f32 = 1.05 MB
  u16*   w2b = (u16*)(regC + 33554432 + 33554432 + 1048576); // 1024*2048 bf16
  u16*   dwb = (u16*)(regC + 33554432 + 33554432 + 1048576 + 4194304); // 32*2048 bf16
  u16*   un  = zxb + 2048;                                   // aliases zxb cols [2048,4096), lda 4416

  cvt_f32_bf16<<<8192,256,0,stream>>>(u,     ub,  8192*1024/4);
  cvt_f32_bf16<<<4416,256,0,stream>>>(w_in,  w1b, 4416*1024/4);
  cvt_f32_bf16<<<2048,256,0,stream>>>(w_out, w2b, 1024*2048/4);
  cvt_f32_bf16<<<64,  256,0,stream>>>(D_w,   dwb, 32*2048/4);

  // zxBCdt = u @ in_proj_w^T  (bf16 out)
  gemm_bt<1,1><<<dim3(35,64),256,0,stream>>>(ub,1024, w1b,1024, zxb,4416, 8192,4416,1024);
  // depthwise conv + silu -> xc (bf16)
  conv_silu<<<9216,256,0,stream>>>(zxb, conv_w, conv_b, xc);
  // Dscal = x_og @ D_w^T  (f32 out)
  gemm_bt<1,0><<<dim3(1,64),256,0,stream>>>(xc,2304, dwb,2048, Dsc,32, 8192,32,2048);
  // bidirectional scan (overwrites ub/w1b region with ypF)
  scan_kernel<<<128,256,0,stream>>>(zxb, xc, dt_bias, A_log, ypF, ypB);
  // combine + D path + RMS + gate -> un (bf16, in-place in zxb)
  fuse_rms<<<8192,256,0,stream>>>(ypF, ypB, xc, zxb, Dsc, D_b, rms_w);
  // out = un @ outproj_w^T  (f32 out)
  gemm_bt<0,0><<<dim3(8,64),256,0,stream>>>(un,4416, w2b,2048, out,1024, 8192,1024,2048);
}

// Round 3
// 678.267 us; speedup vs baseline: 2.3951x; 2.3951x over previous
//
#include <hip/hip_runtime.h>

typedef unsigned short u16;
typedef __attribute__((ext_vector_type(8))) short bf16x8;
typedef __attribute__((ext_vector_type(4))) float f32x4;

__device__ __forceinline__ float bf2f(u16 u){
  union { unsigned int i; float f; } x; x.i = ((unsigned int)u) << 16; return x.f;
}
__device__ __forceinline__ u16 f2bf(float f){
  union { float f; unsigned int i; } x; x.f = f;
  unsigned int r = x.i + 0x7fffu + ((x.i >> 16) & 1u);
  return (u16)(r >> 16);
}

// ---------------- f32 -> bf16 convert (vectorized) ----------------
__global__ __launch_bounds__(256) void cvt_f32_bf16(const float* __restrict__ in,
                                                    u16* __restrict__ out, int n4){
  int i = blockIdx.x*256 + threadIdx.x;
  if (i < n4){
    float4 v = reinterpret_cast<const float4*>(in)[i];
    ushort4 o = make_ushort4(f2bf(v.x), f2bf(v.y), f2bf(v.z), f2bf(v.w));
    reinterpret_cast<ushort4*>(out)[i] = o;
  }
}

// ---------------- bf16 MFMA GEMM: C[M][N] = A[M][K] * Bt[N][K]^T ----
// MODE 0: f32 out (ldc). MODE 1: bf16 out (ldc). MODE 2: split z/xbc/dt (gemm1).
template<int GUARD, int MODE>
__global__ __launch_bounds__(256) void gemm_bt(
    const u16* __restrict__ A, int lda,
    const u16* __restrict__ Bt, int ldb,
    void* __restrict__ Cp, int ldc,
    int M, int N, int K,
    u16* __restrict__ zb, u16* __restrict__ xb, u16* __restrict__ db_)
{
  __shared__ __align__(16) u16 As[128*64];
  __shared__ __align__(16) u16 Bs[128*64];
  const int tid  = threadIdx.x;
  const int wid  = tid >> 6;
  const int lane = tid & 63;
  const int m0 = blockIdx.y * 128;
  const int n0 = blockIdx.x * 128;
  const int wr = wid >> 1, wc = wid & 1;
  const int lq = lane >> 4, lr = lane & 15;

  f32x4 acc[4][4];
  #pragma unroll
  for (int m=0;m<4;m++)
    #pragma unroll
    for (int n=0;n<4;n++) acc[m][n] = (f32x4){0.f,0.f,0.f,0.f};

  const int srow = wid*32 + (lane>>3);
  const int scol = (lane&7)*8;

  for (int k0=0; k0<K; k0+=64){
    #pragma unroll
    for (int i=0;i<4;i++){
      const u16* ga = A + (size_t)(m0 + srow + i*8)*lda + k0 + scol;
      __builtin_amdgcn_global_load_lds(
        (const __attribute__((address_space(1))) void*)ga,
        (__attribute__((address_space(3))) void*)&As[(wid*32+i*8)*64], 16, 0, 0);
    }
    #pragma unroll
    for (int i=0;i<4;i++){
      int gn = n0 + srow + i*8;
      if (GUARD) gn = (gn < N) ? gn : (N-1);
      const u16* gb = Bt + (size_t)gn*ldb + k0 + scol;
      __builtin_amdgcn_global_load_lds(
        (const __attribute__((address_space(1))) void*)gb,
        (__attribute__((address_space(3))) void*)&Bs[(wid*32+i*8)*64], 16, 0, 0);
    }
    __syncthreads();
    #pragma unroll
    for (int kk=0;kk<2;kk++){
      bf16x8 af[4], bfr[4];
      #pragma unroll
      for (int m=0;m<4;m++)
        af[m] = *reinterpret_cast<const bf16x8*>(&As[(wr*64 + m*16 + lr)*64 + kk*32 + lq*8]);
      #pragma unroll
      for (int n=0;n<4;n++)
        bfr[n] = *reinterpret_cast<const bf16x8*>(&Bs[(wc*64 + n*16 + lr)*64 + kk*32 + lq*8]);
      #pragma unroll
      for (int m=0;m<4;m++)
        #pragma unroll
        for (int n=0;n<4;n++)
          acc[m][n] = __builtin_amdgcn_mfma_f32_16x16x32_bf16(af[m], bfr[n], acc[m][n], 0,0,0);
    }
    __syncthreads();
  }

  #pragma unroll
  for (int m=0;m<4;m++){
    int row = m0 + wr*64 + m*16 + lq*4;
    #pragma unroll
    for (int n=0;n<4;n++){
      int col = n0 + wc*64 + n*16 + lr;
      if (!GUARD || col < N){
        #pragma unroll
        for (int j=0;j<4;j++){
          float v = acc[m][n][j];
          size_t r = (size_t)(row+j);
          if (MODE == 0)      ((float*)Cp)[r*ldc + col] = v;
          else if (MODE == 1) ((u16*)Cp)[r*ldc + col] = f2bf(v);
          else {
            u16 bv = f2bf(v);
            if (col < 2048)      zb[r*2048 + col] = bv;
            else if (col < 4352) xb[r*2304 + (col-2048)] = bv;
            else                 db_[r*64 + (col-4352)] = bv;
          }
        }
      }
    }
  }
}

// ---------------- depthwise conv7 (SAME) + bias + SiLU -> bf16 ----------------
// input: xbc[8192][2304] bf16 ; output xc[8192][2304] bf16
__global__ __launch_bounds__(256) void conv_silu(
    const u16* __restrict__ xbc, const float* __restrict__ w,
    const float* __restrict__ bias, u16* __restrict__ xc)
{
  int idx = blockIdx.x*256 + threadIdx.x;   // 8192*288 units of 8 channels
  if (idx >= 8192*288) return;
  int g   = idx % 288;
  int row = idx / 288;
  int l = row & 4095;
  int c = g*8;
  float a[8];
  #pragma unroll
  for (int j=0;j<8;j++) a[j] = bias[c+j];
  #pragma unroll
  for (int t=0;t<7;t++){
    int ls = l + t - 3;
    if (ls >= 0 && ls < 4096){
      bf16x8 v = *reinterpret_cast<const bf16x8*>(&xbc[(size_t)(row + (ls - l))*2304 + c]);
      #pragma unroll
      for (int j=0;j<8;j++) a[j] += bf2f((u16)v[j]) * w[(c+j)*7+t];
    }
  }
  bf16x8 o;
  #pragma unroll
  for (int j=0;j<8;j++){
    float s = a[j]/(1.f+__expf(-a[j]));
    o[j] = (short)f2bf(s);
  }
  *reinterpret_cast<bf16x8*>(&xc[(size_t)row*2304 + c]) = o;
}

// ================= chunked SSD scan (Q=64) =================
// Pass A: per-chunk parallel. G=C.B^T (MFMA), mask, y_intra=Gm.X (MFMA),
// dB=X^T.Bw (MFMA). Stores y_intra (bf16), dB (bf16), chunk dt-sum.
__global__ __launch_bounds__(256) void ssd_chunk(
    const u16* __restrict__ xc, const u16* __restrict__ dtb,
    const float* __restrict__ dt_bias, const float* __restrict__ A_log,
    u16* __restrict__ yP, u16* __restrict__ dB, float* __restrict__ csum, int dir)
{
  const int c  = blockIdx.x & 63;
  const int th = blockIdx.x >> 6;
  const int h  = th & 31;
  const int b  = th >> 5;
  const int tid = threadIdx.x;
  const int wid = tid >> 6;
  const int lane = tid & 63;
  const int lq = lane >> 4, lr = lane & 15;

  __shared__ __align__(16) u16 Cs[64*64];
  __shared__ __align__(16) u16 Bls[64*64];
  __shared__ __align__(16) u16 Xt[64*64];
  __shared__ __align__(16) u16 Gm[64*64];
  __shared__ __align__(16) u16 Bwt[64*64];
  __shared__ float cum[64], dtl[64];

  const float Ah = -__expf(A_log[h]);

  // stage B, C (row-major [i][n])
  for (int e = tid; e < 512; e += 256){
    int i = e >> 3, g = e & 7;
    int l = dir ? (4095 - (c*64+i)) : (c*64+i);
    size_t rb = (size_t)(b*4096 + l)*2304;
    *reinterpret_cast<bf16x8*>(&Bls[i*64+g*8]) =
        *reinterpret_cast<const bf16x8*>(&xc[rb + 2048 + dir*128 + g*8]);
    *reinterpret_cast<bf16x8*>(&Cs[i*64+g*8]) =
        *reinterpret_cast<const bf16x8*>(&xc[rb + 2112 + dir*128 + g*8]);
  }
  // stage X transposed: Xt[p][i]
  for (int e = tid; e < 512; e += 256){
    int i = e & 63, g = e >> 6;
    int l = dir ? (4095 - (c*64+i)) : (c*64+i);
    bf16x8 xv = *reinterpret_cast<const bf16x8*>(&xc[(size_t)(b*4096+l)*2304 + (size_t)h*64 + g*8]);
    #pragma unroll
    for (int j=0;j<8;j++) Xt[(g*8+j)*64 + i] = (u16)xv[j];
  }
  // dt_eff + prefix sum (wave 0)
  if (tid < 64){
    int i = tid;
    int l = dir ? (4095 - (c*64+i)) : (c*64+i);
    float raw = bf2f(dtb[(size_t)(b*4096+l)*64 + dir*32 + h]) + dt_bias[h];
    float dte = (raw > 20.f) ? raw : log1pf(__expf(raw));
    dtl[i] = dte;
    float s = dte;
    #pragma unroll
    for (int off=1; off<64; off<<=1){
      float o = __shfl_up(s, off, 64);
      if (i >= off) s += o;
    }
    cum[i] = s;
    if (i == 63) csum[blockIdx.x] = s;
  }
  __syncthreads();

  // G = C @ B^T  (rows strip wid*16)
  f32x4 g4[4];
  #pragma unroll
  for (int n=0;n<4;n++) g4[n] = (f32x4){0.f,0.f,0.f,0.f};
  #pragma unroll
  for (int kk=0;kk<2;kk++){
    bf16x8 ca = *reinterpret_cast<const bf16x8*>(&Cs[(wid*16+lr)*64 + kk*32 + lq*8]);
    #pragma unroll
    for (int n=0;n<4;n++){
      bf16x8 bb = *reinterpret_cast<const bf16x8*>(&Bls[(n*16+lr)*64 + kk*32 + lq*8]);
      g4[n] = __builtin_amdgcn_mfma_f32_16x16x32_bf16(ca, bb, g4[n], 0,0,0);
    }
  }
  // mask + write Gm bf16 [i][j]
  #pragma unroll
  for (int n=0;n<4;n++){
    #pragma unroll
    for (int r=0;r<4;r++){
      int gi = wid*16 + lq*4 + r;
      int gj = n*16 + lr;
      float wgt = (gj <= gi) ? __expf(Ah*(cum[gi]-cum[gj]))*dtl[gj] : 0.f;
      Gm[gi*64+gj] = f2bf(g4[n][r]*wgt);
    }
  }
  // Bwt[n][j] = exp(Ah*(cum63-cum[j]))*dt[j]*B[j][n]
  float ctot = cum[63];
  for (int e = tid; e < 512; e += 256){
    int j = e & 63, g = e >> 6;
    float wj = __expf(Ah*(ctot - cum[j])) * dtl[j];
    bf16x8 bv = *reinterpret_cast<const bf16x8*>(&Bls[j*64 + g*8]);
    #pragma unroll
    for (int nn=0;nn<8;nn++) Bwt[(g*8+nn)*64 + j] = f2bf(wj * bf2f((u16)bv[nn]));
  }
  __syncthreads();

  // y_intra = Gm @ X  (rows i strip) ; dBacc = Xt @ Bwt^T (rows p strip)
  f32x4 yi[4], db4[4];
  #pragma unroll
  for (int n=0;n<4;n++){ yi[n] = (f32x4){0.f,0.f,0.f,0.f}; db4[n] = (f32x4){0.f,0.f,0.f,0.f}; }
  #pragma unroll
  for (int kk=0;kk<2;kk++){
    bf16x8 ga = *reinterpret_cast<const bf16x8*>(&Gm[(wid*16+lr)*64 + kk*32 + lq*8]);
    bf16x8 xa = *reinterpret_cast<const bf16x8*>(&Xt[(wid*16+lr)*64 + kk*32 + lq*8]);
    #pragma unroll
    for (int n=0;n<4;n++){
      bf16x8 xb = *reinterpret_cast<const bf16x8*>(&Xt[(n*16+lr)*64 + kk*32 + lq*8]);
      yi[n] = __builtin_amdgcn_mfma_f32_16x16x32_bf16(ga, xb, yi[n], 0,0,0);
      bf16x8 wb = *reinterpret_cast<const bf16x8*>(&Bwt[(n*16+lr)*64 + kk*32 + lq*8]);
      db4[n] = __builtin_amdgcn_mfma_f32_16x16x32_bf16(xa, wb, db4[n], 0,0,0);
    }
  }
  // store y_intra: row = b*4096 + c*64 + i, col = h*64 + p
  #pragma unroll
  for (int n=0;n<4;n++){
    #pragma unroll
    for (int r=0;r<4;r++){
      int i = wid*16 + lq*4 + r;
      yP[(size_t)(b*4096 + c*64 + i)*2048 + (size_t)h*64 + n*16 + lr] = f2bf(yi[n][r]);
    }
  }
  // store dB: slot = blockIdx.x, [p][n]
  u16* dst = dB + (size_t)blockIdx.x*4096;
  #pragma unroll
  for (int n=0;n<4;n++){
    #pragma unroll
    for (int r=0;r<4;r++){
      int p = wid*16 + lq*4 + r;
      dst[p*64 + n*16 + lr] = f2bf(db4[n][r]);
    }
  }
}

// Pass B1: sequential h-chain over chunks (f32 regs), slot-shift in-place:
// slot c gets h_in(c+1). Grid per dir: 256 blocks (task x 4 p-quarters).
__global__ __launch_bounds__(256) void ssd_state(
    u16* __restrict__ dB, const float* __restrict__ csum,
    const float* __restrict__ A_log)
{
  const int q = blockIdx.x & 3;
  const int task = blockIdx.x >> 2;
  const int h = task & 31;
  const float Ah = -__expf(A_log[h]);
  const int p  = q*16 + (threadIdx.x >> 4);
  const int nb = (threadIdx.x & 15) * 4;
  float h0=0.f, h1=0.f, h2=0.f, h3=0.f;
  for (int c=0; c<63; ++c){
    float P = __expf(Ah * csum[task*64 + c]);
    u16* ptr = dB + ((size_t)(task*64 + c))*4096 + p*64 + nb;
    ushort4 dv = *reinterpret_cast<const ushort4*>(ptr);
    h0 = P*h0 + bf2f(dv.x);
    h1 = P*h1 + bf2f(dv.y);
    h2 = P*h2 + bf2f(dv.z);
    h3 = P*h3 + bf2f(dv.w);
    *reinterpret_cast<ushort4*>(ptr) = make_ushort4(f2bf(h0),f2bf(h1),f2bf(h2),f2bf(h3));
  }
}

// Pass B2: y += cd[i] * (C @ h_in^T). Parallel per chunk; chunk 0 skipped.
__global__ __launch_bounds__(256) void ssd_yinter(
    const u16* __restrict__ xc, const u16* __restrict__ dtb,
    const float* __restrict__ dt_bias, const float* __restrict__ A_log,
    const u16* __restrict__ dB, u16* __restrict__ yP, int dir)
{
  const int c  = blockIdx.x & 63;
  if (c == 0) return;
  const int th = blockIdx.x >> 6;
  const int h  = th & 31;
  const int b  = th >> 5;
  const int tid = threadIdx.x;
  const int wid = tid >> 6;
  const int lane = tid & 63;
  const int lq = lane >> 4, lr = lane & 15;

  __shared__ __align__(16) u16 Cs[64*64];
  __shared__ __align__(16) u16 Hs[64*64];
  __shared__ float cum[64];

  const float Ah = -__expf(A_log[h]);

  for (int e = tid; e < 512; e += 256){
    int i = e >> 3, g = e & 7;
    int l = dir ? (4095 - (c*64+i)) : (c*64+i);
    *reinterpret_cast<bf16x8*>(&Cs[i*64+g*8]) =
        *reinterpret_cast<const bf16x8*>(&xc[(size_t)(b*4096+l)*2304 + 2112 + dir*128 + g*8]);
    *reinterpret_cast<bf16x8*>(&Hs[e*8]) =
        *reinterpret_cast<const bf16x8*>(&dB[(size_t)(blockIdx.x-1)*4096 + e*8]);
  }
  if (tid < 64){
    int i = tid;
    int l = dir ? (4095 - (c*64+i)) : (c*64+i);
    float raw = bf2f(dtb[(size_t)(b*4096+l)*64 + dir*32 + h]) + dt_bias[h];
    float dte = (raw > 20.f) ? raw : log1pf(__expf(raw));
    float s = dte;
    #pragma unroll
    for (int off=1; off<64; off<<=1){
      float o = __shfl_up(s, off, 64);
      if (i >= off) s += o;
    }
    cum[i] = s;
  }
  __syncthreads();

  f32x4 acc[4];
  #pragma unroll
  for (int n=0;n<4;n++) acc[n] = (f32x4){0.f,0.f,0.f,0.f};
  #pragma unroll
  for (int kk=0;kk<2;kk++){
    bf16x8 ca = *reinterpret_cast<const bf16x8*>(&Cs[(wid*16+lr)*64 + kk*32 + lq*8]);
    #pragma unroll
    for (int n=0;n<4;n++){
      bf16x8 hb = *reinterpret_cast<const bf16x8*>(&Hs[(n*16+lr)*64 + kk*32 + lq*8]);
      acc[n] = __builtin_amdgcn_mfma_f32_16x16x32_bf16(ca, hb, acc[n], 0,0,0);
    }
  }
  #pragma unroll
  for (int n=0;n<4;n++){
    #pragma unroll
    for (int r=0;r<4;r++){
      int i = wid*16 + lq*4 + r;
      float cd = __expf(Ah*cum[i]);
      size_t a = (size_t)(b*4096 + c*64 + i)*2048 + (size_t)h*64 + n*16 + lr;
      yP[a] = f2bf(bf2f(yP[a]) + cd*acc[n][r]);
    }
  }
}

// ---------------- fuse: y-combine(shift/flip) + D*x + RMSNorm + SiLU(z) ------
__global__ __launch_bounds__(256) void fuse_rms(
    const u16* __restrict__ ypF, const u16* __restrict__ ypB,
    const u16* __restrict__ xc, const u16* __restrict__ zbuf,
    u16* __restrict__ un,
    const float* __restrict__ Dscal, const float* __restrict__ D_b,
    const float* __restrict__ rms_w)
{
  const int row = blockIdx.x;      // b*4096 + l
  const int l = row & 4095;
  const int tid = threadIdx.x;
  const int c = tid*8;
  const int hh = tid >> 3;
  float v[8]; float ss = 0.f;
  const bool hasF = (l >= 1);
  const bool hasB = (l <= 4094);
  bf16x8 yf, yb;
  if (hasF) yf = *reinterpret_cast<const bf16x8*>(&ypF[(size_t)(row-1)*2048 + c]);
  if (hasB) yb = *reinterpret_cast<const bf16x8*>(&ypB[(size_t)(row + 4094 - 2*l)*2048 + c]);
  bf16x8 xv = *reinterpret_cast<const bf16x8*>(&xc[(size_t)row*2304 + c]);
  const float dsc = Dscal[(size_t)row*32 + hh] + D_b[hh];
  #pragma unroll
  for (int i=0;i<8;i++){
    float y = hasF ? bf2f((u16)yf[i]) : 0.f;
    if (hasB) y += bf2f((u16)yb[i]);
    y += dsc * bf2f((u16)xv[i]);
    v[i] = y;
    ss += y*y;
  }
  #pragma unroll
  for (int o=1;o<64;o<<=1) ss += __shfl_xor(ss, o, 64);
  __shared__ float sred[4];
  if ((tid & 63) == 0) sred[tid>>6] = ss;
  __syncthreads();
  float rstd = rsqrtf((sred[0]+sred[1]+sred[2]+sred[3]) * (1.f/2048.f) + 1e-5f);
  bf16x8 zv = *reinterpret_cast<const bf16x8*>(&zbuf[(size_t)row*2048 + c]);
  bf16x8 o;
  #pragma unroll
  for (int i=0;i<8;i++){
    float z = bf2f((u16)zv[i]);
    float sz = z / (1.f + __expf(-z));
    o[i] = (short)f2bf(v[i]*rstd*rms_w[c+i]*sz);
  }
  *reinterpret_cast<bf16x8*>(&un[(size_t)row*2048 + c]) = o;
}

extern "C" void kernel_launch(void* const* d_in, const int* in_sizes, int n_in,
                              void* d_out, int out_size, void* d_ws, size_t ws_size,
                              hipStream_t stream)
{
  const float* u       = (const float*)d_in[0];
  const float* w_in    = (const float*)d_in[1];
  const float* conv_w  = (const float*)d_in[2];
  const float* conv_b  = (const float*)d_in[3];
  const float* dt_bias = (const float*)d_in[4];
  const float* A_log   = (const float*)d_in[5];
  const float* D_w     = (const float*)d_in[6];
  const float* D_b     = (const float*)d_in[7];
  const float* rms_w   = (const float*)d_in[8];
  const float* w_out   = (const float*)d_in[9];
  float* out = (float*)d_out;
  (void)in_sizes; (void)n_in; (void)out_size; (void)ws_size;

  char* ws = (char*)d_ws;
  // ---- workspace layout (~174.2 MiB total) ----
  u16*   zbuf = (u16*)(ws);                         // 8192x2048 bf16 = 33.55 MB
  u16*   xbc  = (u16*)(ws + 33554432);              // 8192x2304 bf16 = 37.75 MB (dead after conv -> dB -> un)
  u16*   dtbuf= (u16*)(ws + 71303168);              // 8192x64  bf16 = 1.05 MB
  u16*   xc   = (u16*)(ws + 72351744);              // 8192x2304 bf16 = 37.75 MB
  u16*   ypF  = (u16*)(ws + 110100480);             // 8192x2048 bf16 = 33.55 MB
  u16*   ypB  = (u16*)(ws + 143654912);             // 8192x2048 bf16 = 33.55 MB
  float* Dsc  = (float*)(ws + 177209344);           // 8192x32 f32 = 1.05 MB
  u16*   w2b  = (u16*)(ws + 178257920);             // 1024x2048 bf16 = 4.19 MB
  u16*   dwb  = (u16*)(ws + 182452224);             // 32x2048 bf16 = 0.13 MB
  float* csum = (float*)(ws + 182583296);           // 2 x 4096 f32 = 32 KB
  // aliases
  u16*   ub   = ypF;                                // 8192x1024 (dead after gemm1)
  u16*   w1b  = ypF + (size_t)8192*1024;            // 4416x1024 (dead after gemm1)
  u16*   dB   = xbc;                                // 4096 slots x 4096 bf16 = 33.55 MB per dir
  u16*   un   = xbc;                                // 8192x2048 bf16 (born at fuse)

  cvt_f32_bf16<<<8192,256,0,stream>>>(u,     ub,  8192*1024/4);
  cvt_f32_bf16<<<4416,256,0,stream>>>(w_in,  w1b, 4416*1024/4);
  cvt_f32_bf16<<<2048,256,0,stream>>>(w_out, w2b, 1024*2048/4);
  cvt_f32_bf16<<<64,  256,0,stream>>>(D_w,   dwb, 32*2048/4);

  // zxBCdt = u @ in_proj_w^T  (split into zbuf / xbc / dtbuf)
  gemm_bt<1,2><<<dim3(35,64),256,0,stream>>>(ub,1024, w1b,1024, nullptr,0,
                                             8192,4416,1024, zbuf, xbc, dtbuf);
  // depthwise conv + silu -> xc
  conv_silu<<<9216,256,0,stream>>>(xbc, conv_w, conv_b, xc);
  // Dscal = x_og @ D_w^T  (f32)
  gemm_bt<1,0><<<dim3(1,64),256,0,stream>>>(xc,2304, dwb,2048, Dsc,32,
                                            8192,32,2048, nullptr,nullptr,nullptr);
  // chunked SSD scan, per direction
  for (int dir=0; dir<2; ++dir){
    u16* yP = dir ? ypB : ypF;
    ssd_chunk <<<4096,256,0,stream>>>(xc, dtbuf, dt_bias, A_log, yP, dB, csum + dir*4096, dir);
    ssd_state <<<256, 256,0,stream>>>(dB, csum + dir*4096, A_log);
    ssd_yinter<<<4096,256,0,stream>>>(xc, dtbuf, dt_bias, A_log, dB, yP, dir);
  }
  // combine + D path + RMS + gate -> un
  fuse_rms<<<8192,256,0,stream>>>(ypF, ypB, xc, zbuf, un, Dsc, D_b, rms_w);
  // out = un @ outproj_w^T  (f32)
  gemm_bt<0,0><<<dim3(8,64),256,0,stream>>>(un,2048, w2b,2048, out,1024,
                                            8192,1024,2048, nullptr,nullptr,nullptr);
}

// Round 4
// 469.801 us; speedup vs baseline: 3.4578x; 1.4437x over previous
//
#include <hip/hip_runtime.h>

typedef unsigned short u16;
typedef __attribute__((ext_vector_type(8))) short bf16x8;
typedef __attribute__((ext_vector_type(4))) float f32x4;

__device__ __forceinline__ float bf2f(u16 u){
  union { unsigned int i; float f; } x; x.i = ((unsigned int)u) << 16; return x.f;
}
__device__ __forceinline__ u16 f2bf(float f){
  union { float f; unsigned int i; } x; x.f = f;
  unsigned int r = x.i + 0x7fffu + ((x.i >> 16) & 1u);
  return (u16)(r >> 16);
}

// ---------------- f32 -> bf16 convert (vectorized) ----------------
__global__ __launch_bounds__(256) void cvt_f32_bf16(const float* __restrict__ in,
                                                    u16* __restrict__ out, int n4){
  int i = blockIdx.x*256 + threadIdx.x;
  if (i < n4){
    float4 v = reinterpret_cast<const float4*>(in)[i];
    ushort4 o = make_ushort4(f2bf(v.x), f2bf(v.y), f2bf(v.z), f2bf(v.w));
    reinterpret_cast<ushort4*>(out)[i] = o;
  }
}

// ---------------- conv weight transpose: w[2304][7] -> wtb[7][2304] bf16 -----
__global__ __launch_bounds__(256) void conv_prep(const float* __restrict__ w,
                                                 u16* __restrict__ wtb){
  int i = blockIdx.x*256 + threadIdx.x;
  if (i < 2304*7){
    int ch = i / 7, t = i % 7;
    wtb[t*2304 + ch] = f2bf(w[i]);
  }
}

// ---------------- bf16 MFMA GEMM: C[M][N] = A[M][K] * Bt[N][K]^T ----
// MODE 0: f32 out (ldc). MODE 1: bf16 out (ldc). MODE 2: split z/xbc/dt (gemm1).
// XCD-chunked bijective block swizzle (grid size % 8 == 0 for all launches).
template<int GUARD, int MODE>
__global__ __launch_bounds__(256) void gemm_bt(
    const u16* __restrict__ A, int lda,
    const u16* __restrict__ Bt, int ldb,
    void* __restrict__ Cp, int ldc,
    int M, int N, int K,
    u16* __restrict__ zb, u16* __restrict__ xb, u16* __restrict__ db_)
{
  __shared__ __align__(16) u16 As[128*64];
  __shared__ __align__(16) u16 Bs[128*64];
  const int tid  = threadIdx.x;
  const int wid  = tid >> 6;
  const int lane = tid & 63;
  // XCD swizzle
  const int nwg = gridDim.x * gridDim.y;
  const int bid = blockIdx.y * gridDim.x + blockIdx.x;
  const int q8  = nwg >> 3;
  const int swz = (bid & 7)*q8 + (bid >> 3);
  const int m0 = (swz / gridDim.x) * 128;
  const int n0 = (swz % gridDim.x) * 128;
  const int wr = wid >> 1, wc = wid & 1;
  const int lq = lane >> 4, lr = lane & 15;

  f32x4 acc[4][4];
  #pragma unroll
  for (int m=0;m<4;m++)
    #pragma unroll
    for (int n=0;n<4;n++) acc[m][n] = (f32x4){0.f,0.f,0.f,0.f};

  const int srow = wid*32 + (lane>>3);
  const int scol = (lane&7)*8;

  for (int k0=0; k0<K; k0+=64){
    #pragma unroll
    for (int i=0;i<4;i++){
      const u16* ga = A + (size_t)(m0 + srow + i*8)*lda + k0 + scol;
      __builtin_amdgcn_global_load_lds(
        (const __attribute__((address_space(1))) void*)ga,
        (__attribute__((address_space(3))) void*)&As[(wid*32+i*8)*64], 16, 0, 0);
    }
    #pragma unroll
    for (int i=0;i<4;i++){
      int gn = n0 + srow + i*8;
      if (GUARD) gn = (gn < N) ? gn : (N-1);
      const u16* gb = Bt + (size_t)gn*ldb + k0 + scol;
      __builtin_amdgcn_global_load_lds(
        (const __attribute__((address_space(1))) void*)gb,
        (__attribute__((address_space(3))) void*)&Bs[(wid*32+i*8)*64], 16, 0, 0);
    }
    __syncthreads();
    #pragma unroll
    for (int kk=0;kk<2;kk++){
      bf16x8 af[4], bfr[4];
      #pragma unroll
      for (int m=0;m<4;m++)
        af[m] = *reinterpret_cast<const bf16x8*>(&As[(wr*64 + m*16 + lr)*64 + kk*32 + lq*8]);
      #pragma unroll
      for (int n=0;n<4;n++)
        bfr[n] = *reinterpret_cast<const bf16x8*>(&Bs[(wc*64 + n*16 + lr)*64 + kk*32 + lq*8]);
      #pragma unroll
      for (int m=0;m<4;m++)
        #pragma unroll
        for (int n=0;n<4;n++)
          acc[m][n] = __builtin_amdgcn_mfma_f32_16x16x32_bf16(af[m], bfr[n], acc[m][n], 0,0,0);
    }
    __syncthreads();
  }

  #pragma unroll
  for (int m=0;m<4;m++){
    int row = m0 + wr*64 + m*16 + lq*4;
    #pragma unroll
    for (int n=0;n<4;n++){
      int col = n0 + wc*64 + n*16 + lr;
      if (!GUARD || col < N){
        #pragma unroll
        for (int j=0;j<4;j++){
          float v = acc[m][n][j];
          size_t r = (size_t)(row+j);
          if (MODE == 0)      ((float*)Cp)[r*ldc + col] = v;
          else if (MODE == 1) ((u16*)Cp)[r*ldc + col] = f2bf(v);
          else {
            u16 bv = f2bf(v);
            if (col < 2048)      zb[r*2048 + col] = bv;
            else if (col < 4352) xb[r*2304 + (col-2048)] = bv;
            else                 db_[r*64 + (col-4352)] = bv;
          }
        }
      }
    }
  }
}

// ---------------- depthwise conv7 (SAME) + bias + SiLU -> bf16 ----------------
// input: xbc[8192][2304] bf16, wtb[7][2304] bf16 ; output xc[8192][2304] bf16
// XCD-chunked swizzle: 9216 blocks -> each XCD gets 1152 contiguous blocks
// (1024 contiguous rows) so the 7-tap halo reuse hits its private L2.
__global__ __launch_bounds__(256) void conv_silu(
    const u16* __restrict__ xbc, const u16* __restrict__ wtb,
    const float* __restrict__ bias, u16* __restrict__ xc)
{
  const int bid = blockIdx.x;
  const int sb  = (bid & 7)*1152 + (bid >> 3);
  const int idx = sb*256 + threadIdx.x;       // < 8192*288
  const int g   = idx % 288;
  const int row = idx / 288;
  const int l = row & 4095;
  const int c = g*8;
  float a[8];
  float4 b0 = *reinterpret_cast<const float4*>(&bias[c]);
  float4 b1 = *reinterpret_cast<const float4*>(&bias[c+4]);
  a[0]=b0.x; a[1]=b0.y; a[2]=b0.z; a[3]=b0.w;
  a[4]=b1.x; a[5]=b1.y; a[6]=b1.z; a[7]=b1.w;
  #pragma unroll
  for (int t=0;t<7;t++){
    int ls = l + t - 3;
    if (ls >= 0 && ls < 4096){
      bf16x8 v  = *reinterpret_cast<const bf16x8*>(&xbc[(size_t)(row + t - 3)*2304 + c]);
      bf16x8 wv = *reinterpret_cast<const bf16x8*>(&wtb[t*2304 + c]);
      #pragma unroll
      for (int j=0;j<8;j++) a[j] += bf2f((u16)v[j]) * bf2f((u16)wv[j]);
    }
  }
  bf16x8 o;
  #pragma unroll
  for (int j=0;j<8;j++){
    float s = a[j]/(1.f+__expf(-a[j]));
    o[j] = (short)f2bf(s);
  }
  *reinterpret_cast<bf16x8*>(&xc[(size_t)row*2304 + c]) = o;
}

// ================= chunked SSD scan (Q=64) =================
__global__ __launch_bounds__(256) void ssd_chunk(
    const u16* __restrict__ xc, const u16* __restrict__ dtb,
    const float* __restrict__ dt_bias, const float* __restrict__ A_log,
    u16* __restrict__ yP, u16* __restrict__ dB, float* __restrict__ csum, int dir)
{
  const int c  = blockIdx.x & 63;
  const int th = blockIdx.x >> 6;
  const int h  = th & 31;
  const int b  = th >> 5;
  const int tid = threadIdx.x;
  const int wid = tid >> 6;
  const int lane = tid & 63;
  const int lq = lane >> 4, lr = lane & 15;

  __shared__ __align__(16) u16 Cs[64*64];
  __shared__ __align__(16) u16 Bls[64*64];
  __shared__ __align__(16) u16 Xt[64*64];
  __shared__ __align__(16) u16 Gm[64*64];
  __shared__ __align__(16) u16 Bwt[64*64];
  __shared__ float cum[64], dtl[64];

  const float Ah = -__expf(A_log[h]);

  for (int e = tid; e < 512; e += 256){
    int i = e >> 3, g = e & 7;
    int l = dir ? (4095 - (c*64+i)) : (c*64+i);
    size_t rb = (size_t)(b*4096 + l)*2304;
    *reinterpret_cast<bf16x8*>(&Bls[i*64+g*8]) =
        *reinterpret_cast<const bf16x8*>(&xc[rb + 2048 + dir*128 + g*8]);
    *reinterpret_cast<bf16x8*>(&Cs[i*64+g*8]) =
        *reinterpret_cast<const bf16x8*>(&xc[rb + 2112 + dir*128 + g*8]);
  }
  for (int e = tid; e < 512; e += 256){
    int i = e & 63, g = e >> 6;
    int l = dir ? (4095 - (c*64+i)) : (c*64+i);
    bf16x8 xv = *reinterpret_cast<const bf16x8*>(&xc[(size_t)(b*4096+l)*2304 + (size_t)h*64 + g*8]);
    #pragma unroll
    for (int j=0;j<8;j++) Xt[(g*8+j)*64 + i] = (u16)xv[j];
  }
  if (tid < 64){
    int i = tid;
    int l = dir ? (4095 - (c*64+i)) : (c*64+i);
    float raw = bf2f(dtb[(size_t)(b*4096+l)*64 + dir*32 + h]) + dt_bias[h];
    float dte = (raw > 20.f) ? raw : log1pf(__expf(raw));
    dtl[i] = dte;
    float s = dte;
    #pragma unroll
    for (int off=1; off<64; off<<=1){
      float o = __shfl_up(s, off, 64);
      if (i >= off) s += o;
    }
    cum[i] = s;
    if (i == 63) csum[blockIdx.x] = s;
  }
  __syncthreads();

  f32x4 g4[4];
  #pragma unroll
  for (int n=0;n<4;n++) g4[n] = (f32x4){0.f,0.f,0.f,0.f};
  #pragma unroll
  for (int kk=0;kk<2;kk++){
    bf16x8 ca = *reinterpret_cast<const bf16x8*>(&Cs[(wid*16+lr)*64 + kk*32 + lq*8]);
    #pragma unroll
    for (int n=0;n<4;n++){
      bf16x8 bb = *reinterpret_cast<const bf16x8*>(&Bls[(n*16+lr)*64 + kk*32 + lq*8]);
      g4[n] = __builtin_amdgcn_mfma_f32_16x16x32_bf16(ca, bb, g4[n], 0,0,0);
    }
  }
  #pragma unroll
  for (int n=0;n<4;n++){
    #pragma unroll
    for (int r=0;r<4;r++){
      int gi = wid*16 + lq*4 + r;
      int gj = n*16 + lr;
      float wgt = (gj <= gi) ? __expf(Ah*(cum[gi]-cum[gj]))*dtl[gj] : 0.f;
      Gm[gi*64+gj] = f2bf(g4[n][r]*wgt);
    }
  }
  float ctot = cum[63];
  for (int e = tid; e < 512; e += 256){
    int j = e & 63, g = e >> 6;
    float wj = __expf(Ah*(ctot - cum[j])) * dtl[j];
    bf16x8 bv = *reinterpret_cast<const bf16x8*>(&Bls[j*64 + g*8]);
    #pragma unroll
    for (int nn=0;nn<8;nn++) Bwt[(g*8+nn)*64 + j] = f2bf(wj * bf2f((u16)bv[nn]));
  }
  __syncthreads();

  f32x4 yi[4], db4[4];
  #pragma unroll
  for (int n=0;n<4;n++){ yi[n] = (f32x4){0.f,0.f,0.f,0.f}; db4[n] = (f32x4){0.f,0.f,0.f,0.f}; }
  #pragma unroll
  for (int kk=0;kk<2;kk++){
    bf16x8 ga = *reinterpret_cast<const bf16x8*>(&Gm[(wid*16+lr)*64 + kk*32 + lq*8]);
    bf16x8 xa = *reinterpret_cast<const bf16x8*>(&Xt[(wid*16+lr)*64 + kk*32 + lq*8]);
    #pragma unroll
    for (int n=0;n<4;n++){
      bf16x8 xb = *reinterpret_cast<const bf16x8*>(&Xt[(n*16+lr)*64 + kk*32 + lq*8]);
      yi[n] = __builtin_amdgcn_mfma_f32_16x16x32_bf16(ga, xb, yi[n], 0,0,0);
      bf16x8 wb = *reinterpret_cast<const bf16x8*>(&Bwt[(n*16+lr)*64 + kk*32 + lq*8]);
      db4[n] = __builtin_amdgcn_mfma_f32_16x16x32_bf16(xa, wb, db4[n], 0,0,0);
    }
  }
  #pragma unroll
  for (int n=0;n<4;n++){
    #pragma unroll
    for (int r=0;r<4;r++){
      int i = wid*16 + lq*4 + r;
      yP[(size_t)(b*4096 + c*64 + i)*2048 + (size_t)h*64 + n*16 + lr] = f2bf(yi[n][r]);
    }
  }
  u16* dst = dB + (size_t)blockIdx.x*4096;
  #pragma unroll
  for (int n=0;n<4;n++){
    #pragma unroll
    for (int r=0;r<4;r++){
      int p = wid*16 + lq*4 + r;
      dst[p*64 + n*16 + lr] = f2bf(db4[n][r]);
    }
  }
}

// Pass B1: sequential h-chain over chunks, slot-shift in-place.
__global__ __launch_bounds__(256) void ssd_state(
    u16* __restrict__ dB, const float* __restrict__ csum,
    const float* __restrict__ A_log)
{
  const int q = blockIdx.x & 3;
  const int task = blockIdx.x >> 2;
  const int h = task & 31;
  const float Ah = -__expf(A_log[h]);
  const int p  = q*16 + (threadIdx.x >> 4);
  const int nb = (threadIdx.x & 15) * 4;
  float h0=0.f, h1=0.f, h2=0.f, h3=0.f;
  for (int c=0; c<63; ++c){
    float P = __expf(Ah * csum[task*64 + c]);
    u16* ptr = dB + ((size_t)(task*64 + c))*4096 + p*64 + nb;
    ushort4 dv = *reinterpret_cast<const ushort4*>(ptr);
    h0 = P*h0 + bf2f(dv.x);
    h1 = P*h1 + bf2f(dv.y);
    h2 = P*h2 + bf2f(dv.z);
    h3 = P*h3 + bf2f(dv.w);
    *reinterpret_cast<ushort4*>(ptr) = make_ushort4(f2bf(h0),f2bf(h1),f2bf(h2),f2bf(h3));
  }
}

// Pass B2: y += cd[i] * (C @ h_in^T). chunk 0 skipped.
__global__ __launch_bounds__(256) void ssd_yinter(
    const u16* __restrict__ xc, const u16* __restrict__ dtb,
    const float* __restrict__ dt_bias, const float* __restrict__ A_log,
    const u16* __restrict__ dB, u16* __restrict__ yP, int dir)
{
  const int c  = blockIdx.x & 63;
  if (c == 0) return;
  const int th = blockIdx.x >> 6;
  const int h  = th & 31;
  const int b  = th >> 5;
  const int tid = threadIdx.x;
  const int wid = tid >> 6;
  const int lane = tid & 63;
  const int lq = lane >> 4, lr = lane & 15;

  __shared__ __align__(16) u16 Cs[64*64];
  __shared__ __align__(16) u16 Hs[64*64];
  __shared__ float cum[64];

  const float Ah = -__expf(A_log[h]);

  for (int e = tid; e < 512; e += 256){
    int i = e >> 3, g = e & 7;
    int l = dir ? (4095 - (c*64+i)) : (c*64+i);
    *reinterpret_cast<bf16x8*>(&Cs[i*64+g*8]) =
        *reinterpret_cast<const bf16x8*>(&xc[(size_t)(b*4096+l)*2304 + 2112 + dir*128 + g*8]);
    *reinterpret_cast<bf16x8*>(&Hs[e*8]) =
        *reinterpret_cast<const bf16x8*>(&dB[(size_t)(blockIdx.x-1)*4096 + e*8]);
  }
  if (tid < 64){
    int i = tid;
    int l = dir ? (4095 - (c*64+i)) : (c*64+i);
    float raw = bf2f(dtb[(size_t)(b*4096+l)*64 + dir*32 + h]) + dt_bias[h];
    float dte = (raw > 20.f) ? raw : log1pf(__expf(raw));
    float s = dte;
    #pragma unroll
    for (int off=1; off<64; off<<=1){
      float o = __shfl_up(s, off, 64);
      if (i >= off) s += o;
    }
    cum[i] = s;
  }
  __syncthreads();

  f32x4 acc[4];
  #pragma unroll
  for (int n=0;n<4;n++) acc[n] = (f32x4){0.f,0.f,0.f,0.f};
  #pragma unroll
  for (int kk=0;kk<2;kk++){
    bf16x8 ca = *reinterpret_cast<const bf16x8*>(&Cs[(wid*16+lr)*64 + kk*32 + lq*8]);
    #pragma unroll
    for (int n=0;n<4;n++){
      bf16x8 hb = *reinterpret_cast<const bf16x8*>(&Hs[(n*16+lr)*64 + kk*32 + lq*8]);
      acc[n] = __builtin_amdgcn_mfma_f32_16x16x32_bf16(ca, hb, acc[n], 0,0,0);
    }
  }
  #pragma unroll
  for (int n=0;n<4;n++){
    #pragma unroll
    for (int r=0;r<4;r++){
      int i = wid*16 + lq*4 + r;
      float cd = __expf(Ah*cum[i]);
      size_t a = (size_t)(b*4096 + c*64 + i)*2048 + (size_t)h*64 + n*16 + lr;
      yP[a] = f2bf(bf2f(yP[a]) + cd*acc[n][r]);
    }
  }
}

// ---------------- fuse: y-combine(shift/flip) + D*x + RMSNorm + SiLU(z) ------
__global__ __launch_bounds__(256) void fuse_rms(
    const u16* __restrict__ ypF, const u16* __restrict__ ypB,
    const u16* __restrict__ xc, const u16* __restrict__ zbuf,
    u16* __restrict__ un,
    const float* __restrict__ Dscal, const float* __restrict__ D_b,
    const float* __restrict__ rms_w)
{
  const int row = blockIdx.x;
  const int l = row & 4095;
  const int tid = threadIdx.x;
  const int c = tid*8;
  const int hh = tid >> 3;
  float v[8]; float ss = 0.f;
  const bool hasF = (l >= 1);
  const bool hasB = (l <= 4094);
  bf16x8 yf, yb;
  if (hasF) yf = *reinterpret_cast<const bf16x8*>(&ypF[(size_t)(row-1)*2048 + c]);
  if (hasB) yb = *reinterpret_cast<const bf16x8*>(&ypB[(size_t)(row + 4094 - 2*l)*2048 + c]);
  bf16x8 xv = *reinterpret_cast<const bf16x8*>(&xc[(size_t)row*2304 + c]);
  const float dsc = Dscal[(size_t)row*32 + hh] + D_b[hh];
  #pragma unroll
  for (int i=0;i<8;i++){
    float y = hasF ? bf2f((u16)yf[i]) : 0.f;
    if (hasB) y += bf2f((u16)yb[i]);
    y += dsc * bf2f((u16)xv[i]);
    v[i] = y;
    ss += y*y;
  }
  #pragma unroll
  for (int o=1;o<64;o<<=1) ss += __shfl_xor(ss, o, 64);
  __shared__ float sred[4];
  if ((tid & 63) == 0) sred[tid>>6] = ss;
  __syncthreads();
  float rstd = rsqrtf((sred[0]+sred[1]+sred[2]+sred[3]) * (1.f/2048.f) + 1e-5f);
  bf16x8 zv = *reinterpret_cast<const bf16x8*>(&zbuf[(size_t)row*2048 + c]);
  bf16x8 o;
  #pragma unroll
  for (int i=0;i<8;i++){
    float z = bf2f((u16)zv[i]);
    float sz = z / (1.f + __expf(-z));
    o[i] = (short)f2bf(v[i]*rstd*rms_w[c+i]*sz);
  }
  *reinterpret_cast<bf16x8*>(&un[(size_t)row*2048 + c]) = o;
}

extern "C" void kernel_launch(void* const* d_in, const int* in_sizes, int n_in,
                              void* d_out, int out_size, void* d_ws, size_t ws_size,
                              hipStream_t stream)
{
  const float* u       = (const float*)d_in[0];
  const float* w_in    = (const float*)d_in[1];
  const float* conv_w  = (const float*)d_in[2];
  const float* conv_b  = (const float*)d_in[3];
  const float* dt_bias = (const float*)d_in[4];
  const float* A_log   = (const float*)d_in[5];
  const float* D_w     = (const float*)d_in[6];
  const float* D_b     = (const float*)d_in[7];
  const float* rms_w   = (const float*)d_in[8];
  const float* w_out   = (const float*)d_in[9];
  float* out = (float*)d_out;
  (void)in_sizes; (void)n_in; (void)out_size; (void)ws_size;

  char* ws = (char*)d_ws;
  u16*   zbuf = (u16*)(ws);                         // 8192x2048 bf16
  u16*   xbc  = (u16*)(ws + 33554432);              // 8192x2304 bf16 (dead after conv -> dB -> un)
  u16*   dtbuf= (u16*)(ws + 71303168);              // 8192x64  bf16
  u16*   xc   = (u16*)(ws + 72351744);              // 8192x2304 bf16
  u16*   ypF  = (u16*)(ws + 110100480);             // 8192x2048 bf16
  u16*   ypB  = (u16*)(ws + 143654912);             // 8192x2048 bf16
  float* Dsc  = (float*)(ws + 177209344);           // 8192x32 f32
  u16*   w2b  = (u16*)(ws + 178257920);             // 1024x2048 bf16
  u16*   dwb  = (u16*)(ws + 182452224);             // 32x2048 bf16
  float* csum = (float*)(ws + 182583296);           // 2 x 4096 f32
  u16*   wtb  = (u16*)(ws + 182616064);             // 7x2304 bf16 = 32.3 KB
  // aliases
  u16*   ub   = ypF;
  u16*   w1b  = ypF + (size_t)8192*1024;
  u16*   dB   = xbc;
  u16*   un   = xbc;

  cvt_f32_bf16<<<8192,256,0,stream>>>(u,     ub,  8192*1024/4);
  cvt_f32_bf16<<<4416,256,0,stream>>>(w_in,  w1b, 4416*1024/4);
  cvt_f32_bf16<<<2048,256,0,stream>>>(w_out, w2b, 1024*2048/4);
  cvt_f32_bf16<<<64,  256,0,stream>>>(D_w,   dwb, 32*2048/4);
  conv_prep<<<63,256,0,stream>>>(conv_w, wtb);

  // zxBCdt = u @ in_proj_w^T  (split into zbuf / xbc / dtbuf)
  gemm_bt<1,2><<<dim3(35,64),256,0,stream>>>(ub,1024, w1b,1024, nullptr,0,
                                             8192,4416,1024, zbuf, xbc, dtbuf);
  // depthwise conv + silu -> xc
  conv_silu<<<9216,256,0,stream>>>(xbc, wtb, conv_b, xc);
  // Dscal = x_og @ D_w^T  (f32)
  gemm_bt<1,0><<<dim3(1,64),256,0,stream>>>(xc,2304, dwb,2048, Dsc,32,
                                            8192,32,2048, nullptr,nullptr,nullptr);
  // chunked SSD scan, per direction
  for (int dir=0; dir<2; ++dir){
    u16* yP = dir ? ypB : ypF;
    ssd_chunk <<<4096,256,0,stream>>>(xc, dtbuf, dt_bias, A_log, yP, dB, csum + dir*4096, dir);
    ssd_state <<<256, 256,0,stream>>>(dB, csum + dir*4096, A_log);
    ssd_yinter<<<4096,256,0,stream>>>(xc, dtbuf, dt_bias, A_log, dB, yP, dir);
  }
  // combine + D path + RMS + gate -> un
  fuse_rms<<<8192,256,0,stream>>>(ypF, ypB, xc, zbuf, un, Dsc, D_b, rms_w);
  // out = un @ outproj_w^T  (f32)
  gemm_bt<0,0><<<dim3(8,64),256,0,stream>>>(un,2048, w2b,2048, out,1024,
                                            8192,1024,2048, nullptr,nullptr,nullptr);
}